// Round 7
// baseline (8251.541 us; speedup 1.0000x reference)
//
#include <hip/hip_runtime.h>
#include <math.h>

#define T_STEPS 512
#define BATCH   16
#define DIM     1024
#define M_TOTAL (T_STEPS*BATCH)              // 8192
#define OUT_SEC ((size_t)M_TOTAL*DIM)        // 8388608 floats (output section)
#define BD      (BATCH*DIM)
#define NSLICE  16
#define CNT_STRIDE 32

// ws layout (32-bit words):
//   flags[16][128] @ word 0     (b*128 + s*8 + w), monotonic step tags
//   hx[2][16][1024]@ word 2048  (ping-pong h exchange)
#define WS_FLAGS  0
#define WS_HX     2048
#define WS_WORDS  (2048 + 2*16*1024)         // 34816 words
#define WS_BYTES  ((size_t)WS_WORDS*4)       // 139264 B

// ---------------------------------------------------------------------------
__device__ __forceinline__ float wred64(float v){
  #pragma unroll
  for (int off = 32; off >= 1; off >>= 1) v += __shfl_xor(v, off, 64);
  return v;
}

// ---------------------------------------------------------------------------
// Fused prep: blocks [0,2048) = pre GEMM (pre[t]=x@Wx^T+b -> h section slot t+1)
//             blocks [2048,4096) = entmax-1.5 gate -> output section
__global__ __launch_bounds__(256) void prep_kernel(const float* __restrict__ X,
                                                   const float* __restrict__ Wx,
                                                   const float* __restrict__ bias,
                                                   float* __restrict__ out_h,
                                                   const float* __restrict__ z,
                                                   float* __restrict__ gate_out){
  const int tid = threadIdx.x;
  if (blockIdx.x < 2048){
    __shared__ float a_s[64][17];
    __shared__ float w_s[64][17];
    const int bm = blockIdx.x & 127, bn = blockIdx.x >> 7;
    const int m0 = bm*64, n0 = bn*64;
    const int lr = tid >> 2, lc = (tid & 3) * 4;
    const int tx = tid & 15, ty = tid >> 4;

    float acc[4][4] = {};

    for (int k0 = 0; k0 < DIM; k0 += 16){
      float4 av = *reinterpret_cast<const float4*>(X  + (size_t)(m0+lr)*DIM + k0 + lc);
      float4 wv = *reinterpret_cast<const float4*>(Wx + (size_t)(n0+lr)*DIM + k0 + lc);
      __syncthreads();
      a_s[lr][lc+0]=av.x; a_s[lr][lc+1]=av.y; a_s[lr][lc+2]=av.z; a_s[lr][lc+3]=av.w;
      w_s[lr][lc+0]=wv.x; w_s[lr][lc+1]=wv.y; w_s[lr][lc+2]=wv.z; w_s[lr][lc+3]=wv.w;
      __syncthreads();
      #pragma unroll
      for (int k = 0; k < 16; ++k){
        float af[4], wf[4];
        #pragma unroll
        for (int i = 0; i < 4; ++i) af[i] = a_s[ty*4+i][k];
        #pragma unroll
        for (int j = 0; j < 4; ++j) wf[j] = w_s[tx*4+j][k];
        #pragma unroll
        for (int i = 0; i < 4; ++i)
          #pragma unroll
          for (int j = 0; j < 4; ++j) acc[i][j] = fmaf(af[i], wf[j], acc[i][j]);
      }
    }

    const float4 bv = *reinterpret_cast<const float4*>(bias + n0 + tx*4);
    #pragma unroll
    for (int i = 0; i < 4; ++i){
      float4 v;
      v.x = acc[i][0]+bv.x; v.y = acc[i][1]+bv.y; v.z = acc[i][2]+bv.z; v.w = acc[i][3]+bv.w;
      *reinterpret_cast<float4*>(out_h + (size_t)(m0+ty*4+i+BATCH)*DIM + n0 + tx*4) = v;
    }
  } else {
    const int bid  = blockIdx.x - 2048;
    const int row  = bid * 4 + (tid >> 6);
    const int lane = tid & 63;
    const float* zr = z + (size_t)row * DIM;

    float x[16];
    #pragma unroll
    for (int e = 0; e < 4; ++e){
      float4 v = *reinterpret_cast<const float4*>(zr + e*256 + lane*4);
      x[e*4+0]=v.x; x[e*4+1]=v.y; x[e*4+2]=v.z; x[e*4+3]=v.w;
    }

    float m = x[0];
    #pragma unroll
    for (int i = 1; i < 16; ++i) m = fmaxf(m, x[i]);
    #pragma unroll
    for (int off = 32; off >= 1; off >>= 1) m = fmaxf(m, __shfl_xor(m, off, 64));

    float lo = m - 1.0f, hi = m;
    for (int it = 0; it < 30; ++it){
      float mid = 0.5f*(lo + hi);
      float f = 0.f;
      #pragma unroll
      for (int i = 0; i < 16; ++i) f += fmaxf(x[i] - mid, 0.f);
      f = wred64(f);
      if (f >= 1.0f) lo = mid; else hi = mid;
    }
    float s = 0.f, kc = 0.f;
    #pragma unroll
    for (int i = 0; i < 16; ++i){ if (x[i] > lo){ s += x[i]; kc += 1.f; } }
    s = wred64(s); kc = wred64(kc);
    const float tau = (s - 1.0f) / kc;

    float p[16]; float ps = 0.f;
    #pragma unroll
    for (int i = 0; i < 16; ++i){ p[i] = sqrtf(fmaxf(x[i] - tau, 0.f)); ps += p[i]; }
    ps = wred64(ps);
    const float inv = 1.0f / (ps + 1e-10f);

    float* go = gate_out + (size_t)row * DIM;
    #pragma unroll
    for (int e = 0; e < 4; ++e){
      float4 v; v.x=p[e*4]*inv; v.y=p[e*4+1]*inv; v.z=p[e*4+2]*inv; v.w=p[e*4+3]*inv;
      *reinterpret_cast<float4*>(go + e*256 + lane*4) = v;
    }
  }
}

// ---------------------------------------------------------------------------
#define KA(v) asm volatile("" : "+v"(v.x), "+v"(v.y), "+v"(v.z), "+v"(v.w))

// Kernel C: persistent recurrence, wave-autonomous per-wave flags, all
// cross-block traffic LLC-mediated via sc0 sc1 (VERIFIED semantics, r3-r5).
// No __syncthreads in the loop, no atomic RMW, no XCD assumptions.
// Protocol safety: a wave entering step t polled all 128 flags >= t, which
// implies every wave finished step t-1 (gathered h[t-1]); the only slot a
// step-t writer overwrites is (t+1)&1 = slot of h[t-1]. Deadlock-free since
// every poll target is eventually published (monotone progress).
__global__ __launch_bounds__(512, 1) void rnn_kernel(const float* __restrict__ h0,
                                                     const float* __restrict__ Wh,
                                                     float* __restrict__ out,
                                                     unsigned* __restrict__ ws){
  float* out_h = out + OUT_SEC;
  const int tid  = threadIdx.x;
  const int lane = tid & 63;
  const int w    = tid >> 6;            // wave 0..7
  const int b    = blockIdx.x & 15;     // batch
  const int s    = blockIdx.x >> 4;     // slice
  const int dbase = s*64 + w*8;

  unsigned* flags = ws + WS_FLAGS;
  float*    hx    = (float*)(ws + WS_HX);
  unsigned* myflag = flags + b*128 + s*8 + w;
  const unsigned* pollp = flags + b*128 + lane*2;

  // W_h slice 8 rows x 16 cols (L1-served if not register-resident)
  float4 wreg[8][4];
  #pragma unroll
  for (int r = 0; r < 8; ++r)
    #pragma unroll
    for (int j = 0; j < 4; ++j)
      wreg[r][j] = *reinterpret_cast<const float4*>(
          Wh + (size_t)(dbase + r)*DIM + lane*4 + j*256);

  KA(wreg[0][0]); KA(wreg[0][1]); KA(wreg[0][2]); KA(wreg[0][3]);
  KA(wreg[1][0]); KA(wreg[1][1]); KA(wreg[1][2]); KA(wreg[1][3]);
  KA(wreg[2][0]); KA(wreg[2][1]); KA(wreg[2][2]); KA(wreg[2][3]);
  KA(wreg[3][0]); KA(wreg[3][1]); KA(wreg[3][2]); KA(wreg[3][3]);
  KA(wreg[4][0]); KA(wreg[4][1]); KA(wreg[4][2]); KA(wreg[4][3]);
  KA(wreg[5][0]); KA(wreg[5][1]); KA(wreg[5][2]); KA(wreg[5][3]);
  KA(wreg[6][0]); KA(wreg[6][1]); KA(wreg[6][2]); KA(wreg[6][3]);
  KA(wreg[7][0]); KA(wreg[7][1]); KA(wreg[7][2]); KA(wreg[7][3]);

  // h[0] = h0 in the validated h section
  if (tid < 16)
    reinterpret_cast<float4*>(out_h + (size_t)b*DIM + s*64)[tid] =
        reinterpret_cast<const float4*>(h0 + (size_t)b*DIM + s*64)[tid];

  for (int t = 0; t < T_STEPS; ++t){
    // prefetch pre (h slot t+1) and gate (out slot t) — own region, cached
    float pre_v = 0.f, gate_v = 0.f;
    if (lane < 8){
      const size_t d = dbase + lane;
      pre_v  = out_h[(size_t)(t+1)*BD + (size_t)b*DIM + d];
      gate_v = out  [(size_t)t*BD     + (size_t)b*DIM + d];
    }

    float4 hv0, hv1, hv2, hv3;
    if (t == 0){
      const float* hs = h0 + (size_t)b*DIM + lane*4;
      hv0 = *reinterpret_cast<const float4*>(hs);
      hv1 = *reinterpret_cast<const float4*>(hs + 256);
      hv2 = *reinterpret_cast<const float4*>(hs + 512);
      hv3 = *reinterpret_cast<const float4*>(hs + 768);
    } else {
      // poll 128 per-wave flags (2 per lane) until all >= t
      const unsigned want = (unsigned)t;
      for (;;){
        uint2 f;
        asm volatile("global_load_dwordx2 %0, %1, off sc0 sc1\n\t"
                     "s_waitcnt vmcnt(0)"
                     : "=&v"(f) : "v"(pollp) : "memory");
        const int ok = (f.x >= want) & (f.y >= want);
        if (__all(ok)) break;
      }
      // gather h[t][b] (4KB) from the ping-pong exchange slot
      const float* base = hx + (size_t)(t & 1)*(16*1024) + (size_t)b*DIM;
      const float* a0 = base + lane*4;
      const float* a1 = a0 + 256;
      const float* a2 = a0 + 512;
      const float* a3 = a0 + 768;
      asm volatile(
        "global_load_dwordx4 %0, %4, off sc0 sc1\n\t"
        "global_load_dwordx4 %1, %5, off sc0 sc1\n\t"
        "global_load_dwordx4 %2, %6, off sc0 sc1\n\t"
        "global_load_dwordx4 %3, %7, off sc0 sc1\n\t"
        "s_waitcnt vmcnt(0)"
        : "=&v"(hv0), "=&v"(hv1), "=&v"(hv2), "=&v"(hv3)
        : "v"(a0), "v"(a1), "v"(a2), "v"(a3)
        : "memory");
    }

    // 8 rows x 16 FMA; butterfly reduce; capture row r in lane r
    float myv = 0.f;
    #pragma unroll
    for (int r = 0; r < 8; ++r){
      float a = 0.f;
      const float4 w0 = wreg[r][0], w1 = wreg[r][1],
                   w2 = wreg[r][2], w3 = wreg[r][3];
      a = fmaf(w0.x, hv0.x, fmaf(w0.y, hv0.y, fmaf(w0.z, hv0.z, fmaf(w0.w, hv0.w, a))));
      a = fmaf(w1.x, hv1.x, fmaf(w1.y, hv1.y, fmaf(w1.z, hv1.z, fmaf(w1.w, hv1.w, a))));
      a = fmaf(w2.x, hv2.x, fmaf(w2.y, hv2.y, fmaf(w2.z, hv2.z, fmaf(w2.w, hv2.w, a))));
      a = fmaf(w3.x, hv3.x, fmaf(w3.y, hv3.y, fmaf(w3.z, hv3.z, fmaf(w3.w, hv3.w, a))));
      a += __shfl_xor(a, 1, 64);
      a += __shfl_xor(a, 2, 64);
      a += __shfl_xor(a, 4, 64);
      a += __shfl_xor(a, 8, 64);
      a += __shfl_xor(a, 16, 64);
      a += __shfl_xor(a, 32, 64);
      if (lane == r) myv = a;
    }

    if (lane < 8){
      const float v  = pre_v + myv;
      const float e  = __expf(2.0f * v);
      const float hn = 1.0f - 2.0f / (e + 1.0f);   // tanh(v)
      const size_t d = dbase + lane;
      if (t != T_STEPS - 1){
        float* hp = hx + (size_t)((t+1) & 1)*(16*1024) + (size_t)b*DIM + d;
        asm volatile("global_store_dword %0, %1, off sc0 sc1"
                     :: "v"(hp), "v"(hn) : "memory");
      }
      // validated h + output (cached; read only after kernel end)
      out_h[(size_t)(t+1)*BD + (size_t)b*DIM + d] = hn;
      out  [(size_t)t*BD     + (size_t)b*DIM + d] = hn * gate_v;
    }

    if (t != T_STEPS - 1){
      // drain own stores (exchange data now at LLC), publish own flag
      asm volatile("s_waitcnt vmcnt(0)" ::: "memory");
      if (lane == 0){
        const unsigned tag = (unsigned)(t + 1);
        asm volatile("global_store_dword %0, %1, off sc0 sc1"
                     :: "v"(myflag), "v"(tag) : "memory");
      }
    }
  }
}

// ---------------------------------------------------------------------------
// Fallback (ws too small): round-4 counter-flag kernel (needs 2KB).
__global__ __launch_bounds__(512, 1) void rnn_flag(const float* __restrict__ h0,
                                                   const float* __restrict__ Wh,
                                                   float* __restrict__ out,
                                                   unsigned* __restrict__ prog){
  float* out_h = out + OUT_SEC;
  const int tid  = threadIdx.x;
  const int lane = tid & 63;
  const int w    = tid >> 6;
  const int b    = blockIdx.x >> 4;
  const int s    = blockIdx.x & 15;
  const int dbase = s*64 + w*8;

  float4 wreg[8][4];
  #pragma unroll
  for (int r = 0; r < 8; ++r)
    #pragma unroll
    for (int j = 0; j < 4; ++j)
      wreg[r][j] = *reinterpret_cast<const float4*>(
          Wh + (size_t)(dbase + r)*DIM + lane*4 + j*256);

  if (tid < 16)
    reinterpret_cast<float4*>(out_h + (size_t)b*DIM + s*64)[tid] =
        reinterpret_cast<const float4*>(h0 + (size_t)b*DIM + s*64)[tid];

  unsigned* cnt = &prog[b * CNT_STRIDE];

  for (int t = 0; t < T_STEPS; ++t){
    float pre_v = 0.f, gate_v = 0.f;
    if (lane < 8){
      const size_t d = dbase + lane;
      pre_v  = out_h[(size_t)(t+1)*BD + (size_t)b*DIM + d];
      gate_v = out  [(size_t)t*BD     + (size_t)b*DIM + d];
    }
    if (t > 0){
      if (tid == 0){
        while (__hip_atomic_load(cnt, __ATOMIC_RELAXED, __HIP_MEMORY_SCOPE_AGENT)
               < (unsigned)(NSLICE * t)) { }
      }
      __syncthreads();
    }
    const float* hsrc = (t == 0) ? (h0 + (size_t)b*DIM)
                                 : (out_h + (size_t)t*BD + (size_t)b*DIM);
    const float* a0 = hsrc + lane*4;
    const float* a1 = a0 + 256;
    const float* a2 = a0 + 512;
    const float* a3 = a0 + 768;
    float4 hv0, hv1, hv2, hv3;
    asm volatile(
      "global_load_dwordx4 %0, %4, off sc0 sc1\n\t"
      "global_load_dwordx4 %1, %5, off sc0 sc1\n\t"
      "global_load_dwordx4 %2, %6, off sc0 sc1\n\t"
      "global_load_dwordx4 %3, %7, off sc0 sc1\n\t"
      "s_waitcnt vmcnt(0)"
      : "=&v"(hv0), "=&v"(hv1), "=&v"(hv2), "=&v"(hv3)
      : "v"(a0), "v"(a1), "v"(a2), "v"(a3)
      : "memory");

    float myv = 0.f;
    #pragma unroll
    for (int r = 0; r < 8; ++r){
      float a = 0.f;
      const float4 w0 = wreg[r][0], w1 = wreg[r][1],
                   w2 = wreg[r][2], w3 = wreg[r][3];
      a = fmaf(w0.x, hv0.x, fmaf(w0.y, hv0.y, fmaf(w0.z, hv0.z, fmaf(w0.w, hv0.w, a))));
      a = fmaf(w1.x, hv1.x, fmaf(w1.y, hv1.y, fmaf(w1.z, hv1.z, fmaf(w1.w, hv1.w, a))));
      a = fmaf(w2.x, hv2.x, fmaf(w2.y, hv2.y, fmaf(w2.z, hv2.z, fmaf(w2.w, hv2.w, a))));
      a = fmaf(w3.x, hv3.x, fmaf(w3.y, hv3.y, fmaf(w3.z, hv3.z, fmaf(w3.w, hv3.w, a))));
      a += __shfl_xor(a, 1, 64);
      a += __shfl_xor(a, 2, 64);
      a += __shfl_xor(a, 4, 64);
      a += __shfl_xor(a, 8, 64);
      a += __shfl_xor(a, 16, 64);
      a += __shfl_xor(a, 32, 64);
      if (lane == r) myv = a;
    }

    if (lane < 8){
      const float v  = pre_v + myv;
      const float e  = __expf(2.0f * v);
      const float hn = 1.0f - 2.0f / (e + 1.0f);
      const size_t d = dbase + lane;
      __hip_atomic_store(out_h + (size_t)(t+1)*BD + (size_t)b*DIM + d, hn,
                         __ATOMIC_RELAXED, __HIP_MEMORY_SCOPE_AGENT);
      out[(size_t)t*BD + (size_t)b*DIM + d] = hn * gate_v;
    }

    __syncthreads();
    if (tid == 0){
      asm volatile("s_waitcnt vmcnt(0)" ::: "memory");
      __hip_atomic_fetch_add(cnt, 1u, __ATOMIC_RELAXED, __HIP_MEMORY_SCOPE_AGENT);
    }
  }
}

// ---------------------------------------------------------------------------
extern "C" void kernel_launch(void* const* d_in, const int* in_sizes, int n_in,
                              void* d_out, int out_size, void* d_ws, size_t ws_size,
                              hipStream_t stream){
  (void)in_sizes; (void)n_in; (void)out_size;
  const float* x    = (const float*)d_in[0];
  const float* z    = (const float*)d_in[1];
  const float* h0   = (const float*)d_in[2];
  const float* Wx   = (const float*)d_in[3];
  const float* Wh   = (const float*)d_in[4];
  const float* bias = (const float*)d_in[5];
  float* out   = (float*)d_out;
  float* out_h = out + OUT_SEC;

  const bool big = (ws_size >= WS_BYTES);
  hipMemsetAsync(d_ws, 0, big ? WS_BYTES : (size_t)(BATCH*CNT_STRIDE*4), stream);
  prep_kernel<<<4096, 256, 0, stream>>>(x, Wx, bias, out_h, z, out);
  if (big)
    rnn_kernel<<<256, 512, 0, stream>>>(h0, Wh, out, (unsigned*)d_ws);
  else
    rnn_flag  <<<256, 512, 0, stream>>>(h0, Wh, out, (unsigned*)d_ws);
}

// Round 8
// 2558.693 us; speedup vs baseline: 3.2249x; 3.2249x over previous
//
#include <hip/hip_runtime.h>
#include <math.h>

#define T_STEPS 512
#define BATCH   16
#define DIM     1024
#define M_TOTAL (T_STEPS*BATCH)              // 8192
#define OUT_SEC ((size_t)M_TOTAL*DIM)        // 8388608 floats (output section)
#define BD      (BATCH*DIM)
#define NSLICE  16
#define CNT_STRIDE 32

// ws layout (32-bit words):
//   flags[16][16] @ word 0      (b*16 + s), monotonic step tags, 64B/batch line
//   hx[2][16][1024] @ word 256  (ping-pong h exchange)
#define WS_FLAGS  0
#define WS_HX     256
#define WS_WORDS  (256 + 2*16*1024)          // 33024 words
#define WS_BYTES  ((size_t)WS_WORDS*4)       // 132096 B

// ---------------------------------------------------------------------------
__device__ __forceinline__ float wred64(float v){
  #pragma unroll
  for (int off = 32; off >= 1; off >>= 1) v += __shfl_xor(v, off, 64);
  return v;
}

// ---------------------------------------------------------------------------
// Fused prep: blocks [0,2048) = pre GEMM (pre[t]=x@Wx^T+b -> h section slot t+1)
//             blocks [2048,4096) = entmax-1.5 gate -> output section
__global__ __launch_bounds__(256) void prep_kernel(const float* __restrict__ X,
                                                   const float* __restrict__ Wx,
                                                   const float* __restrict__ bias,
                                                   float* __restrict__ out_h,
                                                   const float* __restrict__ z,
                                                   float* __restrict__ gate_out){
  const int tid = threadIdx.x;
  if (blockIdx.x < 2048){
    __shared__ float a_s[64][17];
    __shared__ float w_s[64][17];
    const int bm = blockIdx.x & 127, bn = blockIdx.x >> 7;
    const int m0 = bm*64, n0 = bn*64;
    const int lr = tid >> 2, lc = (tid & 3) * 4;
    const int tx = tid & 15, ty = tid >> 4;

    float acc[4][4] = {};

    for (int k0 = 0; k0 < DIM; k0 += 16){
      float4 av = *reinterpret_cast<const float4*>(X  + (size_t)(m0+lr)*DIM + k0 + lc);
      float4 wv = *reinterpret_cast<const float4*>(Wx + (size_t)(n0+lr)*DIM + k0 + lc);
      __syncthreads();
      a_s[lr][lc+0]=av.x; a_s[lr][lc+1]=av.y; a_s[lr][lc+2]=av.z; a_s[lr][lc+3]=av.w;
      w_s[lr][lc+0]=wv.x; w_s[lr][lc+1]=wv.y; w_s[lr][lc+2]=wv.z; w_s[lr][lc+3]=wv.w;
      __syncthreads();
      #pragma unroll
      for (int k = 0; k < 16; ++k){
        float af[4], wf[4];
        #pragma unroll
        for (int i = 0; i < 4; ++i) af[i] = a_s[ty*4+i][k];
        #pragma unroll
        for (int j = 0; j < 4; ++j) wf[j] = w_s[tx*4+j][k];
        #pragma unroll
        for (int i = 0; i < 4; ++i)
          #pragma unroll
          for (int j = 0; j < 4; ++j) acc[i][j] = fmaf(af[i], wf[j], acc[i][j]);
      }
    }

    const float4 bv = *reinterpret_cast<const float4*>(bias + n0 + tx*4);
    #pragma unroll
    for (int i = 0; i < 4; ++i){
      float4 v;
      v.x = acc[i][0]+bv.x; v.y = acc[i][1]+bv.y; v.z = acc[i][2]+bv.z; v.w = acc[i][3]+bv.w;
      *reinterpret_cast<float4*>(out_h + (size_t)(m0+ty*4+i+BATCH)*DIM + n0 + tx*4) = v;
    }
  } else {
    const int bid  = blockIdx.x - 2048;
    const int row  = bid * 4 + (tid >> 6);
    const int lane = tid & 63;
    const float* zr = z + (size_t)row * DIM;

    float x[16];
    #pragma unroll
    for (int e = 0; e < 4; ++e){
      float4 v = *reinterpret_cast<const float4*>(zr + e*256 + lane*4);
      x[e*4+0]=v.x; x[e*4+1]=v.y; x[e*4+2]=v.z; x[e*4+3]=v.w;
    }

    float m = x[0];
    #pragma unroll
    for (int i = 1; i < 16; ++i) m = fmaxf(m, x[i]);
    #pragma unroll
    for (int off = 32; off >= 1; off >>= 1) m = fmaxf(m, __shfl_xor(m, off, 64));

    float lo = m - 1.0f, hi = m;
    for (int it = 0; it < 30; ++it){
      float mid = 0.5f*(lo + hi);
      float f = 0.f;
      #pragma unroll
      for (int i = 0; i < 16; ++i) f += fmaxf(x[i] - mid, 0.f);
      f = wred64(f);
      if (f >= 1.0f) lo = mid; else hi = mid;
    }
    float s = 0.f, kc = 0.f;
    #pragma unroll
    for (int i = 0; i < 16; ++i){ if (x[i] > lo){ s += x[i]; kc += 1.f; } }
    s = wred64(s); kc = wred64(kc);
    const float tau = (s - 1.0f) / kc;

    float p[16]; float ps = 0.f;
    #pragma unroll
    for (int i = 0; i < 16; ++i){ p[i] = sqrtf(fmaxf(x[i] - tau, 0.f)); ps += p[i]; }
    ps = wred64(ps);
    const float inv = 1.0f / (ps + 1e-10f);

    float* go = gate_out + (size_t)row * DIM;
    #pragma unroll
    for (int e = 0; e < 4; ++e){
      float4 v; v.x=p[e*4]*inv; v.y=p[e*4+1]*inv; v.z=p[e*4+2]*inv; v.w=p[e*4+3]*inv;
      *reinterpret_cast<float4*>(go + e*256 + lane*4) = v;
    }
  }
}

// ---------------------------------------------------------------------------
#define KA(v) asm volatile("" : "+v"(v.x), "+v"(v.y), "+v"(v.z), "+v"(v.w))

// Kernel C: persistent recurrence = round-4 structure with per-block FLAG
// STORES instead of a fetch_add counter (no RMW serialization), polled as one
// 64B line by lanes 0-15 of wave 0. All-wave vmcnt drain before publish
// (fixes r4's tid0-only-drain race). All cross-block traffic sc0 sc1 (LLC).
__global__ __launch_bounds__(512, 1) void rnn_kernel(const float* __restrict__ h0,
                                                     const float* __restrict__ Wh,
                                                     float* __restrict__ out,
                                                     unsigned* __restrict__ ws){
  float* out_h = out + OUT_SEC;
  const int tid  = threadIdx.x;
  const int lane = tid & 63;
  const int w    = tid >> 6;            // wave 0..7
  const int b    = blockIdx.x >> 4;     // batch
  const int s    = blockIdx.x & 15;     // slice
  const int dbase = s*64 + w*8;

  unsigned* flags  = ws + WS_FLAGS;
  float*    hx     = (float*)(ws + WS_HX);
  unsigned* myflag = flags + b*16 + s;
  const unsigned* pollp = flags + b*16 + tid;   // valid for tid<16

  // W_h slice 8 rows x 16 cols (L1-served if not register-resident)
  float4 wreg[8][4];
  #pragma unroll
  for (int r = 0; r < 8; ++r)
    #pragma unroll
    for (int j = 0; j < 4; ++j)
      wreg[r][j] = *reinterpret_cast<const float4*>(
          Wh + (size_t)(dbase + r)*DIM + lane*4 + j*256);

  KA(wreg[0][0]); KA(wreg[0][1]); KA(wreg[0][2]); KA(wreg[0][3]);
  KA(wreg[1][0]); KA(wreg[1][1]); KA(wreg[1][2]); KA(wreg[1][3]);
  KA(wreg[2][0]); KA(wreg[2][1]); KA(wreg[2][2]); KA(wreg[2][3]);
  KA(wreg[3][0]); KA(wreg[3][1]); KA(wreg[3][2]); KA(wreg[3][3]);
  KA(wreg[4][0]); KA(wreg[4][1]); KA(wreg[4][2]); KA(wreg[4][3]);
  KA(wreg[5][0]); KA(wreg[5][1]); KA(wreg[5][2]); KA(wreg[5][3]);
  KA(wreg[6][0]); KA(wreg[6][1]); KA(wreg[6][2]); KA(wreg[6][3]);
  KA(wreg[7][0]); KA(wreg[7][1]); KA(wreg[7][2]); KA(wreg[7][3]);

  // h[0] = h0 in the validated h section
  if (tid < 16)
    reinterpret_cast<float4*>(out_h + (size_t)b*DIM + s*64)[tid] =
        reinterpret_cast<const float4*>(h0 + (size_t)b*DIM + s*64)[tid];

  for (int t = 0; t < T_STEPS; ++t){
    // prefetch pre (h slot t+1) and gate (out slot t) — own region, cached
    float pre_v = 0.f, gate_v = 0.f;
    if (lane < 8){
      const size_t d = dbase + lane;
      pre_v  = out_h[(size_t)(t+1)*BD + (size_t)b*DIM + d];
      gate_v = out  [(size_t)t*BD     + (size_t)b*DIM + d];
    }

    // wait for all 16 slice flags of this batch (one 64B line, lanes 0-15)
    if (t > 0){
      if (tid < 16){
        const unsigned want = (unsigned)t;
        unsigned v;
        do {
          asm volatile("global_load_dword %0, %1, off sc0 sc1\n\t"
                       "s_waitcnt vmcnt(0)"
                       : "=v"(v) : "v"(pollp) : "memory");
        } while (v < want);
      }
      __syncthreads();
    }

    float4 hv0, hv1, hv2, hv3;
    if (t == 0){
      const float* hs = h0 + (size_t)b*DIM + lane*4;
      hv0 = *reinterpret_cast<const float4*>(hs);
      hv1 = *reinterpret_cast<const float4*>(hs + 256);
      hv2 = *reinterpret_cast<const float4*>(hs + 512);
      hv3 = *reinterpret_cast<const float4*>(hs + 768);
    } else {
      // gather h[t][b] (4KB) from the ping-pong exchange slot
      const float* base = hx + (size_t)(t & 1)*(16*1024) + (size_t)b*DIM;
      const float* a0 = base + lane*4;
      const float* a1 = a0 + 256;
      const float* a2 = a0 + 512;
      const float* a3 = a0 + 768;
      asm volatile(
        "global_load_dwordx4 %0, %4, off sc0 sc1\n\t"
        "global_load_dwordx4 %1, %5, off sc0 sc1\n\t"
        "global_load_dwordx4 %2, %6, off sc0 sc1\n\t"
        "global_load_dwordx4 %3, %7, off sc0 sc1\n\t"
        "s_waitcnt vmcnt(0)"
        : "=&v"(hv0), "=&v"(hv1), "=&v"(hv2), "=&v"(hv3)
        : "v"(a0), "v"(a1), "v"(a2), "v"(a3)
        : "memory");
    }

    // 8 rows x 16 FMA; butterfly reduce; capture row r in lane r
    float myv = 0.f;
    #pragma unroll
    for (int r = 0; r < 8; ++r){
      float a = 0.f;
      const float4 w0 = wreg[r][0], w1 = wreg[r][1],
                   w2 = wreg[r][2], w3 = wreg[r][3];
      a = fmaf(w0.x, hv0.x, fmaf(w0.y, hv0.y, fmaf(w0.z, hv0.z, fmaf(w0.w, hv0.w, a))));
      a = fmaf(w1.x, hv1.x, fmaf(w1.y, hv1.y, fmaf(w1.z, hv1.z, fmaf(w1.w, hv1.w, a))));
      a = fmaf(w2.x, hv2.x, fmaf(w2.y, hv2.y, fmaf(w2.z, hv2.z, fmaf(w2.w, hv2.w, a))));
      a = fmaf(w3.x, hv3.x, fmaf(w3.y, hv3.y, fmaf(w3.z, hv3.z, fmaf(w3.w, hv3.w, a))));
      a += __shfl_xor(a, 1, 64);
      a += __shfl_xor(a, 2, 64);
      a += __shfl_xor(a, 4, 64);
      a += __shfl_xor(a, 8, 64);
      a += __shfl_xor(a, 16, 64);
      a += __shfl_xor(a, 32, 64);
      if (lane == r) myv = a;
    }

    if (lane < 8){
      const float v  = pre_v + myv;
      const float e  = __expf(2.0f * v);
      const float hn = 1.0f - 2.0f / (e + 1.0f);   // tanh(v)
      const size_t d = dbase + lane;
      if (t != T_STEPS - 1){
        float* hp = hx + (size_t)((t+1) & 1)*(16*1024) + (size_t)b*DIM + d;
        asm volatile("global_store_dword %0, %1, off sc0 sc1"
                     :: "v"(hp), "v"(hn) : "memory");
      }
      // validated h + output (cached; read only after kernel end)
      out_h[(size_t)(t+1)*BD + (size_t)b*DIM + d] = hn;
      out  [(size_t)t*BD     + (size_t)b*DIM + d] = hn * gate_v;
    }

    if (t != T_STEPS - 1){
      // every wave drains ITS OWN stores, then block-level publish
      asm volatile("s_waitcnt vmcnt(0)" ::: "memory");
      __syncthreads();
      if (tid == 0){
        const unsigned tag = (unsigned)(t + 1);
        asm volatile("global_store_dword %0, %1, off sc0 sc1"
                     :: "v"(myflag), "v"(tag) : "memory");
      }
    }
  }
}

// ---------------------------------------------------------------------------
// Fallback (ws too small): round-4 counter-flag kernel (needs 2KB).
__global__ __launch_bounds__(512, 1) void rnn_flag(const float* __restrict__ h0,
                                                   const float* __restrict__ Wh,
                                                   float* __restrict__ out,
                                                   unsigned* __restrict__ prog){
  float* out_h = out + OUT_SEC;
  const int tid  = threadIdx.x;
  const int lane = tid & 63;
  const int w    = tid >> 6;
  const int b    = blockIdx.x >> 4;
  const int s    = blockIdx.x & 15;
  const int dbase = s*64 + w*8;

  float4 wreg[8][4];
  #pragma unroll
  for (int r = 0; r < 8; ++r)
    #pragma unroll
    for (int j = 0; j < 4; ++j)
      wreg[r][j] = *reinterpret_cast<const float4*>(
          Wh + (size_t)(dbase + r)*DIM + lane*4 + j*256);

  if (tid < 16)
    reinterpret_cast<float4*>(out_h + (size_t)b*DIM + s*64)[tid] =
        reinterpret_cast<const float4*>(h0 + (size_t)b*DIM + s*64)[tid];

  unsigned* cnt = &prog[b * CNT_STRIDE];

  for (int t = 0; t < T_STEPS; ++t){
    float pre_v = 0.f, gate_v = 0.f;
    if (lane < 8){
      const size_t d = dbase + lane;
      pre_v  = out_h[(size_t)(t+1)*BD + (size_t)b*DIM + d];
      gate_v = out  [(size_t)t*BD     + (size_t)b*DIM + d];
    }
    if (t > 0){
      if (tid == 0){
        while (__hip_atomic_load(cnt, __ATOMIC_RELAXED, __HIP_MEMORY_SCOPE_AGENT)
               < (unsigned)(NSLICE * t)) { }
      }
      __syncthreads();
    }
    const float* hsrc = (t == 0) ? (h0 + (size_t)b*DIM)
                                 : (out_h + (size_t)t*BD + (size_t)b*DIM);
    const float* a0 = hsrc + lane*4;
    const float* a1 = a0 + 256;
    const float* a2 = a0 + 512;
    const float* a3 = a0 + 768;
    float4 hv0, hv1, hv2, hv3;
    asm volatile(
      "global_load_dwordx4 %0, %4, off sc0 sc1\n\t"
      "global_load_dwordx4 %1, %5, off sc0 sc1\n\t"
      "global_load_dwordx4 %2, %6, off sc0 sc1\n\t"
      "global_load_dwordx4 %3, %7, off sc0 sc1\n\t"
      "s_waitcnt vmcnt(0)"
      : "=&v"(hv0), "=&v"(hv1), "=&v"(hv2), "=&v"(hv3)
      : "v"(a0), "v"(a1), "v"(a2), "v"(a3)
      : "memory");

    float myv = 0.f;
    #pragma unroll
    for (int r = 0; r < 8; ++r){
      float a = 0.f;
      const float4 w0 = wreg[r][0], w1 = wreg[r][1],
                   w2 = wreg[r][2], w3 = wreg[r][3];
      a = fmaf(w0.x, hv0.x, fmaf(w0.y, hv0.y, fmaf(w0.z, hv0.z, fmaf(w0.w, hv0.w, a))));
      a = fmaf(w1.x, hv1.x, fmaf(w1.y, hv1.y, fmaf(w1.z, hv1.z, fmaf(w1.w, hv1.w, a))));
      a = fmaf(w2.x, hv2.x, fmaf(w2.y, hv2.y, fmaf(w2.z, hv2.z, fmaf(w2.w, hv2.w, a))));
      a = fmaf(w3.x, hv3.x, fmaf(w3.y, hv3.y, fmaf(w3.z, hv3.z, fmaf(w3.w, hv3.w, a))));
      a += __shfl_xor(a, 1, 64);
      a += __shfl_xor(a, 2, 64);
      a += __shfl_xor(a, 4, 64);
      a += __shfl_xor(a, 8, 64);
      a += __shfl_xor(a, 16, 64);
      a += __shfl_xor(a, 32, 64);
      if (lane == r) myv = a;
    }

    if (lane < 8){
      const float v  = pre_v + myv;
      const float e  = __expf(2.0f * v);
      const float hn = 1.0f - 2.0f / (e + 1.0f);
      const size_t d = dbase + lane;
      __hip_atomic_store(out_h + (size_t)(t+1)*BD + (size_t)b*DIM + d, hn,
                         __ATOMIC_RELAXED, __HIP_MEMORY_SCOPE_AGENT);
      out[(size_t)t*BD + (size_t)b*DIM + d] = hn * gate_v;
    }

    __syncthreads();
    if (tid == 0){
      asm volatile("s_waitcnt vmcnt(0)" ::: "memory");
      __hip_atomic_fetch_add(cnt, 1u, __ATOMIC_RELAXED, __HIP_MEMORY_SCOPE_AGENT);
    }
  }
}

// ---------------------------------------------------------------------------
extern "C" void kernel_launch(void* const* d_in, const int* in_sizes, int n_in,
                              void* d_out, int out_size, void* d_ws, size_t ws_size,
                              hipStream_t stream){
  (void)in_sizes; (void)n_in; (void)out_size;
  const float* x    = (const float*)d_in[0];
  const float* z    = (const float*)d_in[1];
  const float* h0   = (const float*)d_in[2];
  const float* Wx   = (const float*)d_in[3];
  const float* Wh   = (const float*)d_in[4];
  const float* bias = (const float*)d_in[5];
  float* out   = (float*)d_out;
  float* out_h = out + OUT_SEC;

  const bool big = (ws_size >= WS_BYTES);
  hipMemsetAsync(d_ws, 0, big ? WS_BYTES : (size_t)(BATCH*CNT_STRIDE*4), stream);
  prep_kernel<<<4096, 256, 0, stream>>>(x, Wx, bias, out_h, z, out);
  if (big)
    rnn_kernel<<<256, 512, 0, stream>>>(h0, Wh, out, (unsigned*)d_ws);
  else
    rnn_flag  <<<256, 512, 0, stream>>>(h0, Wh, out, (unsigned*)d_ws);
}

// Round 9
// 2135.265 us; speedup vs baseline: 3.8644x; 1.1983x over previous
//
#include <hip/hip_runtime.h>
#include <math.h>

#define T_STEPS 512
#define BATCH   16
#define DIM     1024
#define M_TOTAL (T_STEPS*BATCH)              // 8192
#define OUT_SEC ((size_t)M_TOTAL*DIM)        // 8388608 floats (output section)
#define BD      (BATCH*DIM)
#define NSLICE  16
#define CNT_STRIDE 32

// ws: tagged ping-pong exchange, 2 slots x 16 batches x 1024 packets (8B)
#define TAG_PACKETS ((size_t)2*BD)
#define TAG_BYTES   (TAG_PACKETS*8)          // 256 KB

// ---------------------------------------------------------------------------
__device__ __forceinline__ float wred64(float v){
  #pragma unroll
  for (int off = 32; off >= 1; off >>= 1) v += __shfl_xor(v, off, 64);
  return v;
}

// ---------------------------------------------------------------------------
// Fused prep: blocks [0,2048) = pre GEMM (pre[t]=x@Wx^T+b -> h section slot t+1)
//             blocks [2048,4096) = entmax-1.5 gate -> output section
__global__ __launch_bounds__(256) void prep_kernel(const float* __restrict__ X,
                                                   const float* __restrict__ Wx,
                                                   const float* __restrict__ bias,
                                                   float* __restrict__ out_h,
                                                   const float* __restrict__ z,
                                                   float* __restrict__ gate_out){
  const int tid = threadIdx.x;
  if (blockIdx.x < 2048){
    __shared__ float a_s[64][17];
    __shared__ float w_s[64][17];
    const int bm = blockIdx.x & 127, bn = blockIdx.x >> 7;
    const int m0 = bm*64, n0 = bn*64;
    const int lr = tid >> 2, lc = (tid & 3) * 4;
    const int tx = tid & 15, ty = tid >> 4;

    float acc[4][4] = {};

    for (int k0 = 0; k0 < DIM; k0 += 16){
      float4 av = *reinterpret_cast<const float4*>(X  + (size_t)(m0+lr)*DIM + k0 + lc);
      float4 wv = *reinterpret_cast<const float4*>(Wx + (size_t)(n0+lr)*DIM + k0 + lc);
      __syncthreads();
      a_s[lr][lc+0]=av.x; a_s[lr][lc+1]=av.y; a_s[lr][lc+2]=av.z; a_s[lr][lc+3]=av.w;
      w_s[lr][lc+0]=wv.x; w_s[lr][lc+1]=wv.y; w_s[lr][lc+2]=wv.z; w_s[lr][lc+3]=wv.w;
      __syncthreads();
      #pragma unroll
      for (int k = 0; k < 16; ++k){
        float af[4], wf[4];
        #pragma unroll
        for (int i = 0; i < 4; ++i) af[i] = a_s[ty*4+i][k];
        #pragma unroll
        for (int j = 0; j < 4; ++j) wf[j] = w_s[tx*4+j][k];
        #pragma unroll
        for (int i = 0; i < 4; ++i)
          #pragma unroll
          for (int j = 0; j < 4; ++j) acc[i][j] = fmaf(af[i], wf[j], acc[i][j]);
      }
    }

    const float4 bv = *reinterpret_cast<const float4*>(bias + n0 + tx*4);
    #pragma unroll
    for (int i = 0; i < 4; ++i){
      float4 v;
      v.x = acc[i][0]+bv.x; v.y = acc[i][1]+bv.y; v.z = acc[i][2]+bv.z; v.w = acc[i][3]+bv.w;
      *reinterpret_cast<float4*>(out_h + (size_t)(m0+ty*4+i+BATCH)*DIM + n0 + tx*4) = v;
    }
  } else {
    const int bid  = blockIdx.x - 2048;
    const int row  = bid * 4 + (tid >> 6);
    const int lane = tid & 63;
    const float* zr = z + (size_t)row * DIM;

    float x[16];
    #pragma unroll
    for (int e = 0; e < 4; ++e){
      float4 v = *reinterpret_cast<const float4*>(zr + e*256 + lane*4);
      x[e*4+0]=v.x; x[e*4+1]=v.y; x[e*4+2]=v.z; x[e*4+3]=v.w;
    }

    float m = x[0];
    #pragma unroll
    for (int i = 1; i < 16; ++i) m = fmaxf(m, x[i]);
    #pragma unroll
    for (int off = 32; off >= 1; off >>= 1) m = fmaxf(m, __shfl_xor(m, off, 64));

    float lo = m - 1.0f, hi = m;
    for (int it = 0; it < 30; ++it){
      float mid = 0.5f*(lo + hi);
      float f = 0.f;
      #pragma unroll
      for (int i = 0; i < 16; ++i) f += fmaxf(x[i] - mid, 0.f);
      f = wred64(f);
      if (f >= 1.0f) lo = mid; else hi = mid;
    }
    float s = 0.f, kc = 0.f;
    #pragma unroll
    for (int i = 0; i < 16; ++i){ if (x[i] > lo){ s += x[i]; kc += 1.f; } }
    s = wred64(s); kc = wred64(kc);
    const float tau = (s - 1.0f) / kc;

    float p[16]; float ps = 0.f;
    #pragma unroll
    for (int i = 0; i < 16; ++i){ p[i] = sqrtf(fmaxf(x[i] - tau, 0.f)); ps += p[i]; }
    ps = wred64(ps);
    const float inv = 1.0f / (ps + 1e-10f);

    float* go = gate_out + (size_t)row * DIM;
    #pragma unroll
    for (int e = 0; e < 4; ++e){
      float4 v; v.x=p[e*4]*inv; v.y=p[e*4+1]*inv; v.z=p[e*4+2]*inv; v.w=p[e*4+3]*inv;
      *reinterpret_cast<float4*>(go + e*256 + lane*4) = v;
    }
  }
}

// ---------------------------------------------------------------------------
#define KA(v) asm volatile("" : "+v"(v.x), "+v"(v.y), "+v"(v.z), "+v"(v.w))

// Kernel C: persistent recurrence with SELF-FLAGGING tagged packets.
// 256 blocks = 16 batches x 16 slices, 512 threads. Writers store (value,tag)
// 8B packets to a ping-pong LLC slot — no drain, no flag, no publish chain
// (packet visible => that writer finished its step, so overwrite is safe).
// ONE wave per block polls its batch's 1024 packets (8KB sweep; the final
// sweep IS the gather), unpacks to LDS; other waves read 4KB from LDS.
// Safety: tag-t packet at LLC implies its writer completed the t-1 gather
// (vmcnt(0) precedes compute precedes store), so slot (t+1)&1's previous
// readers are done before any step-t writer overwrites it. 8B-aligned
// dwordx2 stores are atomic (validated r5: no torn reads).
__global__ __launch_bounds__(512, 1) void rnn_tag(const float* __restrict__ h0,
                                                  const float* __restrict__ Wh,
                                                  float* __restrict__ out,
                                                  uint2* __restrict__ tagbuf){
  float* out_h = out + OUT_SEC;
  const int tid  = threadIdx.x;
  const int lane = tid & 63;
  const int w    = tid >> 6;            // wave 0..7
  const int b    = blockIdx.x >> 4;     // batch
  const int s    = blockIdx.x & 15;     // slice
  const int dbase = s*64 + w*8;

  __shared__ float hbuf[2][DIM];        // 8 KB ping-pong broadcast buffer

  // W_h slice 8 rows x 16 cols (L1-served if not register-resident)
  float4 wreg[8][4];
  #pragma unroll
  for (int r = 0; r < 8; ++r)
    #pragma unroll
    for (int j = 0; j < 4; ++j)
      wreg[r][j] = *reinterpret_cast<const float4*>(
          Wh + (size_t)(dbase + r)*DIM + lane*4 + j*256);

  KA(wreg[0][0]); KA(wreg[0][1]); KA(wreg[0][2]); KA(wreg[0][3]);
  KA(wreg[1][0]); KA(wreg[1][1]); KA(wreg[1][2]); KA(wreg[1][3]);
  KA(wreg[2][0]); KA(wreg[2][1]); KA(wreg[2][2]); KA(wreg[2][3]);
  KA(wreg[3][0]); KA(wreg[3][1]); KA(wreg[3][2]); KA(wreg[3][3]);
  KA(wreg[4][0]); KA(wreg[4][1]); KA(wreg[4][2]); KA(wreg[4][3]);
  KA(wreg[5][0]); KA(wreg[5][1]); KA(wreg[5][2]); KA(wreg[5][3]);
  KA(wreg[6][0]); KA(wreg[6][1]); KA(wreg[6][2]); KA(wreg[6][3]);
  KA(wreg[7][0]); KA(wreg[7][1]); KA(wreg[7][2]); KA(wreg[7][3]);

  // h[0] = h0 in the validated h section
  if (tid < 16)
    reinterpret_cast<float4*>(out_h + (size_t)b*DIM + s*64)[tid] =
        reinterpret_cast<const float4*>(h0 + (size_t)b*DIM + s*64)[tid];

  for (int t = 0; t < T_STEPS; ++t){
    // prefetch pre (h slot t+1) and gate (out slot t) — own region, cached
    float pre_v = 0.f, gate_v = 0.f;
    if (lane < 8){
      const size_t d = dbase + lane;
      pre_v  = out_h[(size_t)(t+1)*BD + (size_t)b*DIM + d];
      gate_v = out  [(size_t)t*BD     + (size_t)b*DIM + d];
    }

    float4 hv0, hv1, hv2, hv3;
    if (t == 0){
      const float* hs = h0 + (size_t)b*DIM + lane*4;
      hv0 = *reinterpret_cast<const float4*>(hs);
      hv1 = *reinterpret_cast<const float4*>(hs + 256);
      hv2 = *reinterpret_cast<const float4*>(hs + 512);
      hv3 = *reinterpret_cast<const float4*>(hs + 768);
    } else {
      if (w == 0){
        // wave 0: poll the batch's 1024 tagged packets (8KB); final sweep
        // doubles as the gather. 16 packets per lane.
        const uint2* slot = tagbuf + (size_t)(t & 1)*BD + (size_t)b*DIM;
        const uint2* p0 = slot + lane*4;
        const uint2* p1 = p0 + 256;
        const uint2* p2 = p0 + 512;
        const uint2* p3 = p0 + 768;
        const unsigned want = (unsigned)t;
        float4 q0,q1,q2,q3,q4,q5,q6,q7;
        for (;;){
          asm volatile(
            "global_load_dwordx4 %0, %8, off sc0 sc1\n\t"
            "global_load_dwordx4 %1, %8, off offset:16 sc0 sc1\n\t"
            "global_load_dwordx4 %2, %9, off sc0 sc1\n\t"
            "global_load_dwordx4 %3, %9, off offset:16 sc0 sc1\n\t"
            "global_load_dwordx4 %4, %10, off sc0 sc1\n\t"
            "global_load_dwordx4 %5, %10, off offset:16 sc0 sc1\n\t"
            "global_load_dwordx4 %6, %11, off sc0 sc1\n\t"
            "global_load_dwordx4 %7, %11, off offset:16 sc0 sc1\n\t"
            "s_waitcnt vmcnt(0)"
            : "=&v"(q0), "=&v"(q1), "=&v"(q2), "=&v"(q3),
              "=&v"(q4), "=&v"(q5), "=&v"(q6), "=&v"(q7)
            : "v"(p0), "v"(p1), "v"(p2), "v"(p3)
            : "memory");
          unsigned ok =
            (__float_as_uint(q0.y)==want) & (__float_as_uint(q0.w)==want) &
            (__float_as_uint(q1.y)==want) & (__float_as_uint(q1.w)==want) &
            (__float_as_uint(q2.y)==want) & (__float_as_uint(q2.w)==want) &
            (__float_as_uint(q3.y)==want) & (__float_as_uint(q3.w)==want) &
            (__float_as_uint(q4.y)==want) & (__float_as_uint(q4.w)==want) &
            (__float_as_uint(q5.y)==want) & (__float_as_uint(q5.w)==want) &
            (__float_as_uint(q6.y)==want) & (__float_as_uint(q6.w)==want) &
            (__float_as_uint(q7.y)==want) & (__float_as_uint(q7.w)==want);
          if (__all((int)ok)) break;
        }
        // unpack values and broadcast via LDS
        float* dst = &hbuf[t & 1][0];
        *reinterpret_cast<float4*>(dst + lane*4)       = make_float4(q0.x,q0.z,q1.x,q1.z);
        *reinterpret_cast<float4*>(dst + 256 + lane*4) = make_float4(q2.x,q2.z,q3.x,q3.z);
        *reinterpret_cast<float4*>(dst + 512 + lane*4) = make_float4(q4.x,q4.z,q5.x,q5.z);
        *reinterpret_cast<float4*>(dst + 768 + lane*4) = make_float4(q6.x,q6.z,q7.x,q7.z);
      }
      __syncthreads();
      const float* src = &hbuf[t & 1][0];
      hv0 = *reinterpret_cast<const float4*>(src + lane*4);
      hv1 = *reinterpret_cast<const float4*>(src + 256 + lane*4);
      hv2 = *reinterpret_cast<const float4*>(src + 512 + lane*4);
      hv3 = *reinterpret_cast<const float4*>(src + 768 + lane*4);
    }

    // 8 rows x 16 FMA; butterfly reduce; capture row r in lane r
    float myv = 0.f;
    #pragma unroll
    for (int r = 0; r < 8; ++r){
      float a = 0.f;
      const float4 w0 = wreg[r][0], w1 = wreg[r][1],
                   w2 = wreg[r][2], w3 = wreg[r][3];
      a = fmaf(w0.x, hv0.x, fmaf(w0.y, hv0.y, fmaf(w0.z, hv0.z, fmaf(w0.w, hv0.w, a))));
      a = fmaf(w1.x, hv1.x, fmaf(w1.y, hv1.y, fmaf(w1.z, hv1.z, fmaf(w1.w, hv1.w, a))));
      a = fmaf(w2.x, hv2.x, fmaf(w2.y, hv2.y, fmaf(w2.z, hv2.z, fmaf(w2.w, hv2.w, a))));
      a = fmaf(w3.x, hv3.x, fmaf(w3.y, hv3.y, fmaf(w3.z, hv3.z, fmaf(w3.w, hv3.w, a))));
      a += __shfl_xor(a, 1, 64);
      a += __shfl_xor(a, 2, 64);
      a += __shfl_xor(a, 4, 64);
      a += __shfl_xor(a, 8, 64);
      a += __shfl_xor(a, 16, 64);
      a += __shfl_xor(a, 32, 64);
      if (lane == r) myv = a;
    }

    if (lane < 8){
      const float v  = pre_v + myv;
      const float e  = __expf(2.0f * v);
      const float hn = 1.0f - 2.0f / (e + 1.0f);   // tanh(v)
      const size_t d = dbase + lane;
      if (t != T_STEPS - 1){
        // self-flagging packet (value, t+1) -> ping-pong slot; no drain needed
        const unsigned long long pkt =
            ((unsigned long long)(unsigned)(t + 1) << 32) |
            (unsigned long long)__float_as_uint(hn);
        __hip_atomic_store(
            reinterpret_cast<unsigned long long*>(
                tagbuf + (size_t)((t + 1) & 1)*BD + (size_t)b*DIM + d),
            pkt, __ATOMIC_RELAXED, __HIP_MEMORY_SCOPE_AGENT);
      }
      // validated h + output (cached; read only after kernel end)
      out_h[(size_t)(t+1)*BD + (size_t)b*DIM + d] = hn;
      out  [(size_t)t*BD     + (size_t)b*DIM + d] = hn * gate_v;
    }
  }
}

// ---------------------------------------------------------------------------
// Fallback (ws too small): round-4 counter-flag kernel (needs 2KB). Verified
// 1537 us.
__global__ __launch_bounds__(512, 1) void rnn_flag(const float* __restrict__ h0,
                                                   const float* __restrict__ Wh,
                                                   float* __restrict__ out,
                                                   unsigned* __restrict__ prog){
  float* out_h = out + OUT_SEC;
  const int tid  = threadIdx.x;
  const int lane = tid & 63;
  const int w    = tid >> 6;
  const int b    = blockIdx.x >> 4;
  const int s    = blockIdx.x & 15;
  const int dbase = s*64 + w*8;

  float4 wreg[8][4];
  #pragma unroll
  for (int r = 0; r < 8; ++r)
    #pragma unroll
    for (int j = 0; j < 4; ++j)
      wreg[r][j] = *reinterpret_cast<const float4*>(
          Wh + (size_t)(dbase + r)*DIM + lane*4 + j*256);

  if (tid < 16)
    reinterpret_cast<float4*>(out_h + (size_t)b*DIM + s*64)[tid] =
        reinterpret_cast<const float4*>(h0 + (size_t)b*DIM + s*64)[tid];

  unsigned* cnt = &prog[b * CNT_STRIDE];

  for (int t = 0; t < T_STEPS; ++t){
    float pre_v = 0.f, gate_v = 0.f;
    if (lane < 8){
      const size_t d = dbase + lane;
      pre_v  = out_h[(size_t)(t+1)*BD + (size_t)b*DIM + d];
      gate_v = out  [(size_t)t*BD     + (size_t)b*DIM + d];
    }
    if (t > 0){
      if (tid == 0){
        while (__hip_atomic_load(cnt, __ATOMIC_RELAXED, __HIP_MEMORY_SCOPE_AGENT)
               < (unsigned)(NSLICE * t)) { }
      }
      __syncthreads();
    }
    const float* hsrc = (t == 0) ? (h0 + (size_t)b*DIM)
                                 : (out_h + (size_t)t*BD + (size_t)b*DIM);
    const float* a0 = hsrc + lane*4;
    const float* a1 = a0 + 256;
    const float* a2 = a0 + 512;
    const float* a3 = a0 + 768;
    float4 hv0, hv1, hv2, hv3;
    asm volatile(
      "global_load_dwordx4 %0, %4, off sc0 sc1\n\t"
      "global_load_dwordx4 %1, %5, off sc0 sc1\n\t"
      "global_load_dwordx4 %2, %6, off sc0 sc1\n\t"
      "global_load_dwordx4 %3, %7, off sc0 sc1\n\t"
      "s_waitcnt vmcnt(0)"
      : "=&v"(hv0), "=&v"(hv1), "=&v"(hv2), "=&v"(hv3)
      : "v"(a0), "v"(a1), "v"(a2), "v"(a3)
      : "memory");

    float myv = 0.f;
    #pragma unroll
    for (int r = 0; r < 8; ++r){
      float a = 0.f;
      const float4 w0 = wreg[r][0], w1 = wreg[r][1],
                   w2 = wreg[r][2], w3 = wreg[r][3];
      a = fmaf(w0.x, hv0.x, fmaf(w0.y, hv0.y, fmaf(w0.z, hv0.z, fmaf(w0.w, hv0.w, a))));
      a = fmaf(w1.x, hv1.x, fmaf(w1.y, hv1.y, fmaf(w1.z, hv1.z, fmaf(w1.w, hv1.w, a))));
      a = fmaf(w2.x, hv2.x, fmaf(w2.y, hv2.y, fmaf(w2.z, hv2.z, fmaf(w2.w, hv2.w, a))));
      a = fmaf(w3.x, hv3.x, fmaf(w3.y, hv3.y, fmaf(w3.z, hv3.z, fmaf(w3.w, hv3.w, a))));
      a += __shfl_xor(a, 1, 64);
      a += __shfl_xor(a, 2, 64);
      a += __shfl_xor(a, 4, 64);
      a += __shfl_xor(a, 8, 64);
      a += __shfl_xor(a, 16, 64);
      a += __shfl_xor(a, 32, 64);
      if (lane == r) myv = a;
    }

    if (lane < 8){
      const float v  = pre_v + myv;
      const float e  = __expf(2.0f * v);
      const float hn = 1.0f - 2.0f / (e + 1.0f);
      const size_t d = dbase + lane;
      __hip_atomic_store(out_h + (size_t)(t+1)*BD + (size_t)b*DIM + d, hn,
                         __ATOMIC_RELAXED, __HIP_MEMORY_SCOPE_AGENT);
      out[(size_t)t*BD + (size_t)b*DIM + d] = hn * gate_v;
    }

    __syncthreads();
    if (tid == 0){
      asm volatile("s_waitcnt vmcnt(0)" ::: "memory");
      __hip_atomic_fetch_add(cnt, 1u, __ATOMIC_RELAXED, __HIP_MEMORY_SCOPE_AGENT);
    }
  }
}

// ---------------------------------------------------------------------------
extern "C" void kernel_launch(void* const* d_in, const int* in_sizes, int n_in,
                              void* d_out, int out_size, void* d_ws, size_t ws_size,
                              hipStream_t stream){
  (void)in_sizes; (void)n_in; (void)out_size;
  const float* x    = (const float*)d_in[0];
  const float* z    = (const float*)d_in[1];
  const float* h0   = (const float*)d_in[2];
  const float* Wx   = (const float*)d_in[3];
  const float* Wh   = (const float*)d_in[4];
  const float* bias = (const float*)d_in[5];
  float* out   = (float*)d_out;
  float* out_h = out + OUT_SEC;

  const bool big = (ws_size >= TAG_BYTES);
  hipMemsetAsync(d_ws, 0, big ? TAG_BYTES : (size_t)(BATCH*CNT_STRIDE*4), stream);
  prep_kernel<<<4096, 256, 0, stream>>>(x, Wx, bias, out_h, z, out);
  if (big)
    rnn_tag <<<256, 512, 0, stream>>>(h0, Wh, out, (uint2*)d_ws);
  else
    rnn_flag<<<256, 512, 0, stream>>>(h0, Wh, out, (unsigned*)d_ws);
}

// Round 10
// 1229.306 us; speedup vs baseline: 6.7124x; 1.7370x over previous
//
#include <hip/hip_runtime.h>
#include <math.h>

#define T_STEPS 512
#define BATCH   16
#define DIM     1024
#define M_TOTAL (T_STEPS*BATCH)              // 8192
#define OUT_SEC ((size_t)M_TOTAL*DIM)        // 8388608 floats (output section)
#define BD      (BATCH*DIM)
#define NSLICE  16
#define CNT_STRIDE 32

// ws: tagged ping-pong exchange, 2 slots x 16 batches x 1024 packets (8B)
#define TAG_PACKETS ((size_t)2*BD)
#define TAG_BYTES   (TAG_PACKETS*8)          // 256 KB

// ---------------------------------------------------------------------------
__device__ __forceinline__ float wred64(float v){
  #pragma unroll
  for (int off = 32; off >= 1; off >>= 1) v += __shfl_xor(v, off, 64);
  return v;
}

// ---------------------------------------------------------------------------
// Fused prep: blocks [0,2048) = pre GEMM (pre[t]=x@Wx^T+b -> h section slot t+1)
//             blocks [2048,4096) = entmax-1.5 gate -> output section
__global__ __launch_bounds__(256) void prep_kernel(const float* __restrict__ X,
                                                   const float* __restrict__ Wx,
                                                   const float* __restrict__ bias,
                                                   float* __restrict__ out_h,
                                                   const float* __restrict__ z,
                                                   float* __restrict__ gate_out){
  const int tid = threadIdx.x;
  if (blockIdx.x < 2048){
    __shared__ float a_s[64][17];
    __shared__ float w_s[64][17];
    const int bm = blockIdx.x & 127, bn = blockIdx.x >> 7;
    const int m0 = bm*64, n0 = bn*64;
    const int lr = tid >> 2, lc = (tid & 3) * 4;
    const int tx = tid & 15, ty = tid >> 4;

    float acc[4][4] = {};

    for (int k0 = 0; k0 < DIM; k0 += 16){
      float4 av = *reinterpret_cast<const float4*>(X  + (size_t)(m0+lr)*DIM + k0 + lc);
      float4 wv = *reinterpret_cast<const float4*>(Wx + (size_t)(n0+lr)*DIM + k0 + lc);
      __syncthreads();
      a_s[lr][lc+0]=av.x; a_s[lr][lc+1]=av.y; a_s[lr][lc+2]=av.z; a_s[lr][lc+3]=av.w;
      w_s[lr][lc+0]=wv.x; w_s[lr][lc+1]=wv.y; w_s[lr][lc+2]=wv.z; w_s[lr][lc+3]=wv.w;
      __syncthreads();
      #pragma unroll
      for (int k = 0; k < 16; ++k){
        float af[4], wf[4];
        #pragma unroll
        for (int i = 0; i < 4; ++i) af[i] = a_s[ty*4+i][k];
        #pragma unroll
        for (int j = 0; j < 4; ++j) wf[j] = w_s[tx*4+j][k];
        #pragma unroll
        for (int i = 0; i < 4; ++i)
          #pragma unroll
          for (int j = 0; j < 4; ++j) acc[i][j] = fmaf(af[i], wf[j], acc[i][j]);
      }
    }

    const float4 bv = *reinterpret_cast<const float4*>(bias + n0 + tx*4);
    #pragma unroll
    for (int i = 0; i < 4; ++i){
      float4 v;
      v.x = acc[i][0]+bv.x; v.y = acc[i][1]+bv.y; v.z = acc[i][2]+bv.z; v.w = acc[i][3]+bv.w;
      *reinterpret_cast<float4*>(out_h + (size_t)(m0+ty*4+i+BATCH)*DIM + n0 + tx*4) = v;
    }
  } else {
    const int bid  = blockIdx.x - 2048;
    const int row  = bid * 4 + (tid >> 6);
    const int lane = tid & 63;
    const float* zr = z + (size_t)row * DIM;

    float x[16];
    #pragma unroll
    for (int e = 0; e < 4; ++e){
      float4 v = *reinterpret_cast<const float4*>(zr + e*256 + lane*4);
      x[e*4+0]=v.x; x[e*4+1]=v.y; x[e*4+2]=v.z; x[e*4+3]=v.w;
    }

    float m = x[0];
    #pragma unroll
    for (int i = 1; i < 16; ++i) m = fmaxf(m, x[i]);
    #pragma unroll
    for (int off = 32; off >= 1; off >>= 1) m = fmaxf(m, __shfl_xor(m, off, 64));

    float lo = m - 1.0f, hi = m;
    for (int it = 0; it < 30; ++it){
      float mid = 0.5f*(lo + hi);
      float f = 0.f;
      #pragma unroll
      for (int i = 0; i < 16; ++i) f += fmaxf(x[i] - mid, 0.f);
      f = wred64(f);
      if (f >= 1.0f) lo = mid; else hi = mid;
    }
    float s = 0.f, kc = 0.f;
    #pragma unroll
    for (int i = 0; i < 16; ++i){ if (x[i] > lo){ s += x[i]; kc += 1.f; } }
    s = wred64(s); kc = wred64(kc);
    const float tau = (s - 1.0f) / kc;

    float p[16]; float ps = 0.f;
    #pragma unroll
    for (int i = 0; i < 16; ++i){ p[i] = sqrtf(fmaxf(x[i] - tau, 0.f)); ps += p[i]; }
    ps = wred64(ps);
    const float inv = 1.0f / (ps + 1e-10f);

    float* go = gate_out + (size_t)row * DIM;
    #pragma unroll
    for (int e = 0; e < 4; ++e){
      float4 v; v.x=p[e*4]*inv; v.y=p[e*4+1]*inv; v.z=p[e*4+2]*inv; v.w=p[e*4+3]*inv;
      *reinterpret_cast<float4*>(go + e*256 + lane*4) = v;
    }
  }
}

// ---------------------------------------------------------------------------
#define KA(v) asm volatile("" : "+v"(v.x), "+v"(v.y), "+v"(v.z), "+v"(v.w))

// Kernel C: persistent recurrence, self-flagging packets + DISTRIBUTED poll.
// Thread tid polls only ITS OWN 2 packets (one dwordx4/iter); exit when both
// tags == t; __syncthreads converges the block; 8B/thread LDS write + 16
// float read redistributes. No flags, no drains, no gather phase.
// Reduction: 10-shuffle fold (rows split across lane halves at xor32/16/8,
// then xor4/2/1) — lane 8r holds row r fully reduced.
__global__ __launch_bounds__(512, 1) void rnn_tag(const float* __restrict__ h0,
                                                  const float* __restrict__ Wh,
                                                  float* __restrict__ out,
                                                  uint2* __restrict__ tagbuf){
  float* out_h = out + OUT_SEC;
  const int tid  = threadIdx.x;
  const int lane = tid & 63;
  const int w    = tid >> 6;            // wave 0..7
  const int b    = blockIdx.x >> 4;     // batch
  const int s    = blockIdx.x & 15;     // slice
  const int dbase = s*64 + w*8;

  __shared__ float hbuf[2][DIM];        // 8 KB ping-pong broadcast buffer

  // W_h slice 8 rows x 16 cols (L1-served if not register-resident)
  float4 wreg[8][4];
  #pragma unroll
  for (int r = 0; r < 8; ++r)
    #pragma unroll
    for (int j = 0; j < 4; ++j)
      wreg[r][j] = *reinterpret_cast<const float4*>(
          Wh + (size_t)(dbase + r)*DIM + lane*4 + j*256);

  KA(wreg[0][0]); KA(wreg[0][1]); KA(wreg[0][2]); KA(wreg[0][3]);
  KA(wreg[1][0]); KA(wreg[1][1]); KA(wreg[1][2]); KA(wreg[1][3]);
  KA(wreg[2][0]); KA(wreg[2][1]); KA(wreg[2][2]); KA(wreg[2][3]);
  KA(wreg[3][0]); KA(wreg[3][1]); KA(wreg[3][2]); KA(wreg[3][3]);
  KA(wreg[4][0]); KA(wreg[4][1]); KA(wreg[4][2]); KA(wreg[4][3]);
  KA(wreg[5][0]); KA(wreg[5][1]); KA(wreg[5][2]); KA(wreg[5][3]);
  KA(wreg[6][0]); KA(wreg[6][1]); KA(wreg[6][2]); KA(wreg[6][3]);
  KA(wreg[7][0]); KA(wreg[7][1]); KA(wreg[7][2]); KA(wreg[7][3]);

  // h[0] = h0 in the validated h section (output slot 0)
  if (tid < 16)
    reinterpret_cast<float4*>(out_h + (size_t)b*DIM + s*64)[tid] =
        reinterpret_cast<const float4*>(h0 + (size_t)b*DIM + s*64)[tid];

  const int myrow   = lane >> 3;            // 0..7
  const bool active = ((lane & 7) == 0);    // 8 store lanes per wave

  for (int t = 0; t < T_STEPS; ++t){
    // prefetch pre (h slot t+1) and gate (out slot t) for this lane's row
    float pre_v = 0.f, gate_v = 0.f;
    if (active){
      const size_t d = dbase + myrow;
      pre_v  = out_h[(size_t)(t+1)*BD + (size_t)b*DIM + d];
      gate_v = out  [(size_t)t*BD     + (size_t)b*DIM + d];
    }

    // ---- acquire h[t][b] into LDS (distributed) ----
    if (t == 0){
      const float2 hl = *reinterpret_cast<const float2*>(h0 + (size_t)b*DIM + 2*tid);
      *reinterpret_cast<float2*>(&hbuf[0][2*tid]) = hl;
    } else {
      const uint2* pp = tagbuf + (size_t)(t & 1)*BD + (size_t)b*DIM + 2*tid;
      const unsigned want = (unsigned)t;
      float4 q;
      do {
        asm volatile("global_load_dwordx4 %0, %1, off sc0 sc1\n\t"
                     "s_waitcnt vmcnt(0)"
                     : "=&v"(q) : "v"(pp) : "memory");
      } while (__float_as_uint(q.y) != want || __float_as_uint(q.w) != want);
      *reinterpret_cast<float2*>(&hbuf[t & 1][2*tid]) = make_float2(q.x, q.z);
    }
    __syncthreads();

    const float* src = &hbuf[t & 1][0];
    const float4 hv0 = *reinterpret_cast<const float4*>(src + lane*4);
    const float4 hv1 = *reinterpret_cast<const float4*>(src + 256 + lane*4);
    const float4 hv2 = *reinterpret_cast<const float4*>(src + 512 + lane*4);
    const float4 hv3 = *reinterpret_cast<const float4*>(src + 768 + lane*4);

    // ---- partials: v[r] = dot(wreg[r], hv) over this lane's 16 cols ----
    float v0,v1,v2,v3,v4,v5,v6,v7;
    {
      #define DOTROW(R, OUTV)                                            \
        { const float4 w0=wreg[R][0], w1=wreg[R][1],                     \
                       w2=wreg[R][2], w3=wreg[R][3];                     \
          float a_ = 0.f;                                                \
          a_ = fmaf(w0.x,hv0.x,fmaf(w0.y,hv0.y,fmaf(w0.z,hv0.z,fmaf(w0.w,hv0.w,a_)))); \
          a_ = fmaf(w1.x,hv1.x,fmaf(w1.y,hv1.y,fmaf(w1.z,hv1.z,fmaf(w1.w,hv1.w,a_)))); \
          a_ = fmaf(w2.x,hv2.x,fmaf(w2.y,hv2.y,fmaf(w2.z,hv2.z,fmaf(w2.w,hv2.w,a_)))); \
          a_ = fmaf(w3.x,hv3.x,fmaf(w3.y,hv3.y,fmaf(w3.z,hv3.z,fmaf(w3.w,hv3.w,a_)))); \
          OUTV = a_; }
      DOTROW(0,v0) DOTROW(1,v1) DOTROW(2,v2) DOTROW(3,v3)
      DOTROW(4,v4) DOTROW(5,v5) DOTROW(6,v6) DOTROW(7,v7)
      #undef DOTROW
    }

    // ---- 10-shuffle folded reduction ----
    const bool sA = (lane & 32) != 0;
    float a0 = (sA? v4 : v0) + __shfl_xor(sA? v0 : v4, 32, 64);
    float a1 = (sA? v5 : v1) + __shfl_xor(sA? v1 : v5, 32, 64);
    float a2 = (sA? v6 : v2) + __shfl_xor(sA? v2 : v6, 32, 64);
    float a3 = (sA? v7 : v3) + __shfl_xor(sA? v3 : v7, 32, 64);
    const bool sB = (lane & 16) != 0;
    float b0 = (sB? a2 : a0) + __shfl_xor(sB? a0 : a2, 16, 64);
    float b1 = (sB? a3 : a1) + __shfl_xor(sB? a1 : a3, 16, 64);
    const bool sC = (lane & 8) != 0;
    float c0 = (sC? b1 : b0) + __shfl_xor(sC? b0 : b1, 8, 64);
    c0 += __shfl_xor(c0, 4, 64);
    c0 += __shfl_xor(c0, 2, 64);
    c0 += __shfl_xor(c0, 1, 64);
    // lane (8*r) holds row r = (lane>>3) fully reduced

    if (active){
      const float v  = pre_v + c0;
      const float e  = __expf(2.0f * v);
      const float hn = 1.0f - 2.0f / (e + 1.0f);   // tanh(v)
      const size_t d = dbase + myrow;
      if (t != T_STEPS - 1){
        // self-flagging packet (value, t+1) -> ping-pong slot; no drain
        const unsigned long long pkt =
            ((unsigned long long)(unsigned)(t + 1) << 32) |
            (unsigned long long)__float_as_uint(hn);
        __hip_atomic_store(
            reinterpret_cast<unsigned long long*>(
                tagbuf + (size_t)((t + 1) & 1)*BD + (size_t)b*DIM + d),
            pkt, __ATOMIC_RELAXED, __HIP_MEMORY_SCOPE_AGENT);
      }
      // validated h + output (cached; read only after kernel end)
      out_h[(size_t)(t+1)*BD + (size_t)b*DIM + d] = hn;
      out  [(size_t)t*BD     + (size_t)b*DIM + d] = hn * gate_v;
    }
  }
}

// ---------------------------------------------------------------------------
// Fallback (ws too small): round-4 counter-flag kernel (needs 2KB). Verified
// 1537 us.
__global__ __launch_bounds__(512, 1) void rnn_flag(const float* __restrict__ h0,
                                                   const float* __restrict__ Wh,
                                                   float* __restrict__ out,
                                                   unsigned* __restrict__ prog){
  float* out_h = out + OUT_SEC;
  const int tid  = threadIdx.x;
  const int lane = tid & 63;
  const int w    = tid >> 6;
  const int b    = blockIdx.x >> 4;
  const int s    = blockIdx.x & 15;
  const int dbase = s*64 + w*8;

  float4 wreg[8][4];
  #pragma unroll
  for (int r = 0; r < 8; ++r)
    #pragma unroll
    for (int j = 0; j < 4; ++j)
      wreg[r][j] = *reinterpret_cast<const float4*>(
          Wh + (size_t)(dbase + r)*DIM + lane*4 + j*256);

  if (tid < 16)
    reinterpret_cast<float4*>(out_h + (size_t)b*DIM + s*64)[tid] =
        reinterpret_cast<const float4*>(h0 + (size_t)b*DIM + s*64)[tid];

  unsigned* cnt = &prog[b * CNT_STRIDE];

  for (int t = 0; t < T_STEPS; ++t){
    float pre_v = 0.f, gate_v = 0.f;
    if (lane < 8){
      const size_t d = dbase + lane;
      pre_v  = out_h[(size_t)(t+1)*BD + (size_t)b*DIM + d];
      gate_v = out  [(size_t)t*BD     + (size_t)b*DIM + d];
    }
    if (t > 0){
      if (tid == 0){
        while (__hip_atomic_load(cnt, __ATOMIC_RELAXED, __HIP_MEMORY_SCOPE_AGENT)
               < (unsigned)(NSLICE * t)) { }
      }
      __syncthreads();
    }
    const float* hsrc = (t == 0) ? (h0 + (size_t)b*DIM)
                                 : (out_h + (size_t)t*BD + (size_t)b*DIM);
    const float* a0 = hsrc + lane*4;
    const float* a1 = a0 + 256;
    const float* a2 = a0 + 512;
    const float* a3 = a0 + 768;
    float4 hv0, hv1, hv2, hv3;
    asm volatile(
      "global_load_dwordx4 %0, %4, off sc0 sc1\n\t"
      "global_load_dwordx4 %1, %5, off sc0 sc1\n\t"
      "global_load_dwordx4 %2, %6, off sc0 sc1\n\t"
      "global_load_dwordx4 %3, %7, off sc0 sc1\n\t"
      "s_waitcnt vmcnt(0)"
      : "=&v"(hv0), "=&v"(hv1), "=&v"(hv2), "=&v"(hv3)
      : "v"(a0), "v"(a1), "v"(a2), "v"(a3)
      : "memory");

    float myv = 0.f;
    #pragma unroll
    for (int r = 0; r < 8; ++r){
      float a = 0.f;
      const float4 w0 = wreg[r][0], w1 = wreg[r][1],
                   w2 = wreg[r][2], w3 = wreg[r][3];
      a = fmaf(w0.x, hv0.x, fmaf(w0.y, hv0.y, fmaf(w0.z, hv0.z, fmaf(w0.w, hv0.w, a))));
      a = fmaf(w1.x, hv1.x, fmaf(w1.y, hv1.y, fmaf(w1.z, hv1.z, fmaf(w1.w, hv1.w, a))));
      a = fmaf(w2.x, hv2.x, fmaf(w2.y, hv2.y, fmaf(w2.z, hv2.z, fmaf(w2.w, hv2.w, a))));
      a = fmaf(w3.x, hv3.x, fmaf(w3.y, hv3.y, fmaf(w3.z, hv3.z, fmaf(w3.w, hv3.w, a))));
      a += __shfl_xor(a, 1, 64);
      a += __shfl_xor(a, 2, 64);
      a += __shfl_xor(a, 4, 64);
      a += __shfl_xor(a, 8, 64);
      a += __shfl_xor(a, 16, 64);
      a += __shfl_xor(a, 32, 64);
      if (lane == r) myv = a;
    }

    if (lane < 8){
      const float v  = pre_v + myv;
      const float e  = __expf(2.0f * v);
      const float hn = 1.0f - 2.0f / (e + 1.0f);
      const size_t d = dbase + lane;
      __hip_atomic_store(out_h + (size_t)(t+1)*BD + (size_t)b*DIM + d, hn,
                         __ATOMIC_RELAXED, __HIP_MEMORY_SCOPE_AGENT);
      out[(size_t)t*BD + (size_t)b*DIM + d] = hn * gate_v;
    }

    __syncthreads();
    if (tid == 0){
      asm volatile("s_waitcnt vmcnt(0)" ::: "memory");
      __hip_atomic_fetch_add(cnt, 1u, __ATOMIC_RELAXED, __HIP_MEMORY_SCOPE_AGENT);
    }
  }
}

// ---------------------------------------------------------------------------
extern "C" void kernel_launch(void* const* d_in, const int* in_sizes, int n_in,
                              void* d_out, int out_size, void* d_ws, size_t ws_size,
                              hipStream_t stream){
  (void)in_sizes; (void)n_in; (void)out_size;
  const float* x    = (const float*)d_in[0];
  const float* z    = (const float*)d_in[1];
  const float* h0   = (const float*)d_in[2];
  const float* Wx   = (const float*)d_in[3];
  const float* Wh   = (const float*)d_in[4];
  const float* bias = (const float*)d_in[5];
  float* out   = (float*)d_out;
  float* out_h = out + OUT_SEC;

  const bool big = (ws_size >= TAG_BYTES);
  hipMemsetAsync(d_ws, 0, big ? TAG_BYTES : (size_t)(BATCH*CNT_STRIDE*4), stream);
  prep_kernel<<<4096, 256, 0, stream>>>(x, Wx, bias, out_h, z, out);
  if (big)
    rnn_tag <<<256, 512, 0, stream>>>(h0, Wh, out, (uint2*)d_ws);
  else
    rnn_flag<<<256, 512, 0, stream>>>(h0, Wh, out, (unsigned*)d_ws);
}